// Round 1
// 724.240 us; speedup vs baseline: 1.6266x; 1.6266x over previous
//
#include <hip/hip_runtime.h>
#include <hip/hip_bf16.h>
#include <stdint.h>

// R3: Cl(3,0) ≅ M2(C) isomorphism. out = blade-decode( Xc @ Wc ) where Xc,Wc are
// 2x2-complex-block matrices (Pauli rep). Complex GEMM [4096,4096,4096] = 0.55 TFLOP
// — exactly HALF the 64-blade-pair formulation (1.10 TFLOP). 4 real MFMA paths:
// Cr = Ar*Br - Ai*Bi, Ci = Ar*Bi + Ai*Br, with (-Ai) via bf16 sign-mask XOR.
// k packed as [r=0 | r=1] halves; output cols packed as [q=0 | q=1] halves; each
// wave owns both q-halves of its d-range so the blade decode is thread-local.
// Staging/fragment/C-layout conventions copied verbatim from the verified R2 kernel.

#define BATCH 2048
#define DIN 2048
#define DD 2048
#define K2 4096  // 2*DIN  (k-dim of packed complex operands)
#define R2R 4096 // 2*BATCH (rows of packed A)

typedef __attribute__((ext_vector_type(8))) __bf16 bf16x8;
typedef __attribute__((ext_vector_type(4))) float f32x4;
typedef __attribute__((ext_vector_type(4))) unsigned int u32x4;

#define NEG 0x80008000u

__device__ __forceinline__ unsigned short f2bf(float f) {
  unsigned int u = __float_as_uint(f);
  u = (u + 0x7FFFu + ((u >> 16) & 1u)) >> 16;  // RNE
  return (unsigned short)u;
}

__device__ __forceinline__ u32x4 pack8(const float* s) {
  u32x4 p;
#pragma unroll
  for (int w = 0; w < 4; ++w)
    p[w] = (unsigned)f2bf(s[2 * w]) | ((unsigned)f2bf(s[2 * w + 1]) << 16);
  return p;
}

__device__ __forceinline__ void gl_lds16(const void* g, void* l) {
  __builtin_amdgcn_global_load_lds((__attribute__((address_space(1))) void*)g,
                                   (__attribute__((address_space(3))) void*)l,
                                   16, 0, 0);
}

union FragU {
  u32x4 u;
  bf16x8 v;
};

// ---------------------------------------------------------------------------
// pack_x: x [8*B, DIN] fp32 -> Ar, Ai [2B, 2*DIN] bf16.
// Row 2b+p, col r*DIN + l holds (0.5x) entry M_pr of the Pauli rep of x[:,b,l]:
//   M11=(x0+x3)+i(x7+x4)  M12=(x1-x5)+i(x6-x2)
//   M21=(x1+x5)+i(x6+x2)  M22=(x0-x3)+i(x7-x4)
// The global 1/2 of the inverse transform is folded here (exact: exponent shift).
// grid: BATCH blocks x 256 threads, 8 l's per thread. All loads/stores 16B coalesced.
__global__ void pack_x(const float* __restrict__ x,
                       unsigned short* __restrict__ Ar,
                       unsigned short* __restrict__ Ai) {
  const int b = blockIdx.x;
  const int l0 = threadIdx.x * 8;
  float v[8][8];
#pragma unroll
  for (int i = 0; i < 8; ++i) {
    const float4* p = (const float4*)&x[((size_t)i * BATCH + b) * DIN + l0];
    float4 a = p[0], c = p[1];
    v[i][0] = a.x; v[i][1] = a.y; v[i][2] = a.z; v[i][3] = a.w;
    v[i][4] = c.x; v[i][5] = c.y; v[i][6] = c.z; v[i][7] = c.w;
  }
  const size_t r0 = (size_t)(2 * b) * K2;
  const size_t r1 = (size_t)(2 * b + 1) * K2;
  float t[8];
#pragma unroll
  for (int e = 0; e < 8; ++e) t[e] = 0.5f * (v[0][e] + v[3][e]);
  *(u32x4*)&Ar[r0 + l0] = pack8(t);
#pragma unroll
  for (int e = 0; e < 8; ++e) t[e] = 0.5f * (v[1][e] - v[5][e]);
  *(u32x4*)&Ar[r0 + DIN + l0] = pack8(t);
#pragma unroll
  for (int e = 0; e < 8; ++e) t[e] = 0.5f * (v[1][e] + v[5][e]);
  *(u32x4*)&Ar[r1 + l0] = pack8(t);
#pragma unroll
  for (int e = 0; e < 8; ++e) t[e] = 0.5f * (v[0][e] - v[3][e]);
  *(u32x4*)&Ar[r1 + DIN + l0] = pack8(t);
#pragma unroll
  for (int e = 0; e < 8; ++e) t[e] = 0.5f * (v[7][e] + v[4][e]);
  *(u32x4*)&Ai[r0 + l0] = pack8(t);
#pragma unroll
  for (int e = 0; e < 8; ++e) t[e] = 0.5f * (v[6][e] - v[2][e]);
  *(u32x4*)&Ai[r0 + DIN + l0] = pack8(t);
#pragma unroll
  for (int e = 0; e < 8; ++e) t[e] = 0.5f * (v[6][e] + v[2][e]);
  *(u32x4*)&Ai[r1 + l0] = pack8(t);
#pragma unroll
  for (int e = 0; e < 8; ++e) t[e] = 0.5f * (v[7][e] - v[4][e]);
  *(u32x4*)&Ai[r1 + DIN + l0] = pack8(t);
}

// ---------------------------------------------------------------------------
// pack_w: W [DIN, 8*DD] fp32 -> Br, Bi [2*DD, 2*DIN] bf16 (transposed for GEMM).
// Bt[q*DD + d][r*DIN + l] = entry M_rq of Pauli rep of W[l, :, d].
// Each of the 8 (mat,q,r) quadrant-planes is a transposed +/- combo of exactly
// two W blade-planes; 4 pair-jobs via blockIdx.z:
//   z=0: planes(0,3) -> Br: sum->(q0,r0), diff->(q1,r1)
//   z=1: planes(1,5) -> Br: sum->(q0,r1), diff->(q1,r0)
//   z=2: planes(7,4) -> Bi: sum->(q0,r0), diff->(q1,r1)
//   z=3: planes(6,2) -> Bi: sum->(q0,r1), diff->(q1,r0)
__constant__ int c_pw[4][2] = {{0, 3}, {1, 5}, {7, 4}, {6, 2}};

__global__ void pack_w(const float* __restrict__ W,
                       unsigned short* __restrict__ Br,
                       unsigned short* __restrict__ Bi) {
  __shared__ float ts[64][65], td[64][65];
  const int z = blockIdx.z;
  const int p0 = c_pw[z][0], p1 = c_pw[z][1];
  unsigned short* dst = (z < 2) ? Br : Bi;
  const int rs = z & 1;       // sum col-region (r)
  const int rd = rs ^ 1;      // diff col-region
  const int d0 = blockIdx.x * 64;
  const int l0 = blockIdx.y * 64;
  const int tid = threadIdx.x;
  {
    const int row = tid >> 4;        // l-local (+16j)
    const int col = (tid & 15) * 4;  // d-local
#pragma unroll
    for (int j = 0; j < 4; ++j) {
      const size_t base = (size_t)(l0 + row + j * 16) * (8 * DD);
      float4 a = *(const float4*)&W[base + (size_t)p0 * DD + d0 + col];
      float4 b = *(const float4*)&W[base + (size_t)p1 * DD + d0 + col];
      ts[row + j * 16][col + 0] = a.x + b.x;
      ts[row + j * 16][col + 1] = a.y + b.y;
      ts[row + j * 16][col + 2] = a.z + b.z;
      ts[row + j * 16][col + 3] = a.w + b.w;
      td[row + j * 16][col + 0] = a.x - b.x;
      td[row + j * 16][col + 1] = a.y - b.y;
      td[row + j * 16][col + 2] = a.z - b.z;
      td[row + j * 16][col + 3] = a.w - b.w;
    }
  }
  __syncthreads();
  {
    const int rc = (tid & 7) * 8;  // l-chunk of 8
    int c = tid >> 3;              // d-local 0..31, then +32
#pragma unroll
    for (int h = 0; h < 2; ++h, c += 32) {
      float s[8], dl[8];
#pragma unroll
      for (int w = 0; w < 8; ++w) {
        s[w] = ts[rc + w][c];
        dl[w] = td[rc + w][c];
      }
      *(u32x4*)&dst[(size_t)(d0 + c) * K2 + rs * DIN + l0 + rc] = pack8(s);
      *(u32x4*)&dst[(size_t)(DD + d0 + c) * K2 + rd * DIN + l0 + rc] = pack8(dl);
    }
  }
}

// ---------------------------------------------------------------------------
// Complex GEMM: Yc = Xc @ Wc as 4 real bf16 MFMA paths, fused blade decode.
// Block tile: 128 A-rows x 128 c-cols (64 d x 2 q); 4 waves 2x2, wave 64x64.
// LDS 64 KB single-buffered (4 x [128 rows][8 x 16B chunks], XOR-swizzled via
// pre-swizzled global source exactly as R2). grid (32, 32).
__global__ __launch_bounds__(256, 2) void cplx_gemm(
    const unsigned short* __restrict__ Ar, const unsigned short* __restrict__ Ai,
    const unsigned short* __restrict__ Br, const unsigned short* __restrict__ Bi,
    const float* __restrict__ bias, float* __restrict__ out) {
  __shared__ u32x4 ldsAr[1024], ldsAi[1024], ldsBr[1024], ldsBi[1024];  // 64 KB

  const int tid = threadIdx.x;
  const int tn = blockIdx.x;  // d-tile (64 d each)
  const int tm = blockIdx.y;  // row-tile (128 rows each)
  const int wid = tid >> 6;
  const int lane = tid & 63;
  const int wr = wid & 1;
  const int wc = wid >> 1;
  const int lrow = lane & 15;
  const int q4 = lane >> 4;
  const int l7 = lane & 7;
  const u32x4 nmask = {NEG, NEG, NEG, NEG};

  f32x4 accR[4][4] = {};  // [mt][nt], nt = q*2 + ntd
  f32x4 accI[4][4] = {};

  const size_t arow0 = (size_t)tm * 128;
  const int d0 = tn * 64;

  for (int k0 = 0; k0 < K2; k0 += 64) {
    // Stage 4 x 1024 chunks, 4 insts/thread each. Slot L holds logical chunk
    // (L&7)^((L>>3)&7) of row L>>3 (XOR swizzle on the GLOBAL source address).
#pragma unroll
    for (int t = 0; t < 4; ++t) {
      const int L = (t * 4 + wid) * 64 + lane;
      const int m = L >> 3;
      const int c = (L & 7) ^ (m & 7);
      const size_t ao = (arow0 + m) * K2 + (k0 + c * 8);
      gl_lds16(Ar + ao, &ldsAr[(t * 4 + wid) * 64]);
      gl_lds16(Ai + ao, &ldsAi[(t * 4 + wid) * 64]);
      // ldsB rows 0..63 <- Bt rows d0..d0+63 (q=0); rows 64..127 <- DD+d0.. (q=1)
      const size_t bo = ((size_t)((m >> 6) * DD + d0 + (m & 63))) * K2 + (k0 + c * 8);
      gl_lds16(Br + bo, &ldsBr[(t * 4 + wid) * 64]);
      gl_lds16(Bi + bo, &ldsBi[(t * 4 + wid) * 64]);
    }
    __syncthreads();

#pragma unroll
    for (int kk = 0; kk < 2; ++kk) {
      const int p = (kk * 4 + q4) ^ l7;
      FragU arf[4], aif[4], brf[4], bif[4];
#pragma unroll
      for (int mt = 0; mt < 4; ++mt) {
        const int ml = wr * 64 + mt * 16 + lrow;
        arf[mt].u = ldsAr[ml * 8 + p];
        aif[mt].u = ldsAi[ml * 8 + p];
      }
#pragma unroll
      for (int nt = 0; nt < 4; ++nt) {
        const int nl = (nt >> 1) * 64 + wc * 32 + (nt & 1) * 16 + lrow;
        brf[nt].u = ldsBr[nl * 8 + p];
        bif[nt].u = ldsBi[nl * 8 + p];
      }
#pragma unroll
      for (int mt = 0; mt < 4; ++mt) {
        FragU ain;
        ain.u = aif[mt].u ^ nmask;  // -Ai for the Cr path
#pragma unroll
        for (int nt = 0; nt < 4; ++nt) {
          accR[mt][nt] = __builtin_amdgcn_mfma_f32_16x16x32_bf16(
              arf[mt].v, brf[nt].v, accR[mt][nt], 0, 0, 0);
          accR[mt][nt] = __builtin_amdgcn_mfma_f32_16x16x32_bf16(
              ain.v, bif[nt].v, accR[mt][nt], 0, 0, 0);
          accI[mt][nt] = __builtin_amdgcn_mfma_f32_16x16x32_bf16(
              arf[mt].v, bif[nt].v, accI[mt][nt], 0, 0, 0);
          accI[mt][nt] = __builtin_amdgcn_mfma_f32_16x16x32_bf16(
              aif[mt].v, brf[nt].v, accI[mt][nt], 0, 0, 0);
        }
      }
    }
    __syncthreads();
  }

  // Epilogue: thread-local blade decode. C/D layout col=lane&15, row=q4*4+reg.
  // Rows pair (2b,2b+1) = adjacent regs; q pairs = nt vs nt+2 of same thread.
  // 1/2 already folded into pack_x.
  const size_t ks = (size_t)BATCH * DD;
#pragma unroll
  for (int ntd = 0; ntd < 2; ++ntd) {
    const int d = d0 + wc * 32 + ntd * 16 + lrow;
    float bv[8];
#pragma unroll
    for (int k = 0; k < 8; ++k) bv[k] = bias[k * DD + d];
#pragma unroll
    for (int mt = 0; mt < 4; ++mt) {
      const int rowbase = tm * 128 + wr * 64 + mt * 16 + q4 * 4;  // even
      const f32x4 R0 = accR[mt][ntd], R1 = accR[mt][2 + ntd];
      const f32x4 I0 = accI[mt][ntd], I1 = accI[mt][2 + ntd];
#pragma unroll
      for (int j = 0; j < 2; ++j) {
        const int b = (rowbase >> 1) + j;
        const float y00r = R0[2 * j], y10r = R0[2 * j + 1];
        const float y01r = R1[2 * j], y11r = R1[2 * j + 1];
        const float y00i = I0[2 * j], y10i = I0[2 * j + 1];
        const float y01i = I1[2 * j], y11i = I1[2 * j + 1];
        float* o = out + (size_t)b * DD + d;
        o[0]          = (y00r + y11r) + bv[0];  // scalar
        o[ks]         = (y01r + y10r) + bv[1];  // e1
        o[2 * ks]     = (y10i - y01i) + bv[2];  // e2
        o[3 * ks]     = (y00r - y11r) + bv[3];  // e3
        o[4 * ks]     = (y00i - y11i) + bv[4];  // e12
        o[5 * ks]     = (y10r - y01r) + bv[5];  // e13
        o[6 * ks]     = (y01i + y10i) + bv[6];  // e23
        o[7 * ks]     = (y00i + y11i) + bv[7];  // e123
      }
    }
  }
}

extern "C" void kernel_launch(void* const* d_in, const int* in_sizes, int n_in,
                              void* d_out, int out_size, void* d_ws,
                              size_t ws_size, hipStream_t stream) {
  const float* x = (const float*)d_in[0];     // [16384][2048]
  const float* W = (const float*)d_in[1];     // [2048][16384]
  const float* bias = (const float*)d_in[2];  // [16384]
  float* out = (float*)d_out;                 // [16384][2048]

  unsigned short* Arp = (unsigned short*)d_ws;           // 33.5 MB each
  unsigned short* Aip = Arp + (size_t)R2R * K2;
  unsigned short* Brp = Aip + (size_t)R2R * K2;
  unsigned short* Bip = Brp + (size_t)(2 * DD) * K2;     // total 134 MB = same as R2

  pack_x<<<BATCH, 256, 0, stream>>>(x, Arp, Aip);
  pack_w<<<dim3(DD / 64, DIN / 64, 4), 256, 0, stream>>>(W, Brp, Bip);
  cplx_gemm<<<dim3(DD / 64, R2R / 128), 256, 0, stream>>>(Arp, Aip, Brp, Bip,
                                                          bias, out);
}